// Round 13
// baseline (2619.131 us; speedup 1.0000x reference)
//
#include <hip/hip_runtime.h>

// DeepRLSNet: batched RLS. B=64, N=T=2000, TAPS=64.
// Per step:
//   lam = clip(lambdas[t], 1e-4, 0.9999)
//   Px = P@x ; den = lam + x.Px ; g = Px/den ; y = w.x
//   w += g*(d-y) ; P = (P - outer(g, x@P))/lam   (honest x@P — R2 post-mortem)
//
// R13: SINGLE-WAVE blocks (64 blocks x 64 threads) — the R12 counters showed
// ~60% of each round is stall structural to the 4-wave layout (s_barrier
// skew + LDS pipe contention + cross-wave round-trip). One wave per block:
//  - lane r owns FULL rows Q[r][:], QT[r][:] (32 f2 VGPRs each), replicated
//    w (for the y-dot) + distributed w_r (for the final store).
//  - cross-lane traffic = 2 scalar ds_writes + broadcast b128 reads; the
//    only sync is `s_waitcnt lgkmcnt(0)` (intra-wave LDS fence) — NO
//    s_barrier anywhere in the loop. DS ops are in-order per wave.
//  - den / y / all scalars computed all-lane REDUNDANTLY from identical
//    broadcast bits -> bit-uniform, zero reduce chains (no DPP/swizzle).
//  - transpose invariant (bitwise QT == Q^T, proven load-bearing by the
//    R10/R11 bisect): lane r's Q[r][c] -= fl(t_r * xQ[c]) and lane c's
//    QT[c][r] -= fl(t_r * xQ[c]) use identical factor bits (own dot ==
//    LDS broadcast; fma multiplies exactly internally), so both sides
//    round identically. w replicas stay uniform (uniform t, err).
//  - x staged through a 2-deep LDS buffer; distance-4 register prefetch
//    (4 rounds ~2000+ cyc >> 900 cyc HBM latency).
// sigma-space: P = sig*Q, sig *= 1/lam per step (lam table precomputed).

#define B_ 64
#define N_ 2000
#define TAPS_ 64
#define STEPS_ 2000

typedef float f2 __attribute__((ext_vector_type(2)));

__device__ __forceinline__ f2 pk2(float v) { f2 r; r.x = v; r.y = v; return r; }

__device__ __forceinline__ void lds_fence() {
    // intra-wave LDS producer->consumer ordering; no s_barrier needed
    asm volatile("s_waitcnt lgkmcnt(0)" ::: "memory");
}

__device__ __forceinline__ float clipl(float v) {
    return fminf(fmaxf(v, 1e-4f), 0.9999f);
}

// 1/v via v_rcp_f32 + one Newton step (~0.5 ulp).
__device__ __forceinline__ float rcp_nr(float v) {
    float r = __builtin_amdgcn_rcpf(v);
    float e = fmaf(-v, r, 1.0f);
    return fmaf(r, e, r);
}

__global__ __launch_bounds__(64, 1) void rls_kernel(
    const float* __restrict__ x_seq,   // [B, N, TAPS]
    const float* __restrict__ d_seq,   // [B, N]
    const float* __restrict__ lambdas, // [T]
    float* __restrict__ y_out,         // [B, N]
    float* __restrict__ w_out)         // [B, TAPS]
{
    const int b    = blockIdx.x;
    const int lane = threadIdx.x;      // row index 0..63

    __shared__ __align__(16) float  xbuf[2][TAPS_];
    __shared__ __align__(16) float  qxbuf[TAPS_];
    __shared__ __align__(16) float  xqbuf[TAPS_];
    __shared__ __align__(16) float  d_lds[STEPS_];
    __shared__ __align__(16) float2 lam2[STEPS_];   // {clip(lam), rcp_nr(clip(lam))}

    const float* xb = x_seq + (size_t)b * N_ * TAPS_;
    const float* db = d_seq + (size_t)b * N_;

    for (int idx = lane; idx < STEPS_; idx += 64) {
        d_lds[idx] = db[idx];
        const float lc = clipl(lambdas[idx]);
        lam2[idx] = make_float2(lc, rcp_nr(lc));
    }

    // full rows in registers
    f2 Q[32], QT[32], w[32];
    #pragma unroll
    for (int j = 0; j < 32; ++j) {
        f2 id;
        id.x = (2 * j     == lane) ? 1.0f : 0.0f;
        id.y = (2 * j + 1 == lane) ? 1.0f : 0.0f;
        Q[j] = id; QT[j] = id; w[j] = pk2(0.0f);
    }
    float w_r = 0.0f;   // distributed w (for final store); bitwise == w[lane]
    float sig = 1.0f;   // P = sig * Q

    // prologue: x_0 -> xbuf[0]; x_1..x_4 into prefetch regs
    xbuf[0][lane] = xb[lane];
    float pf1 = xb[1 * TAPS_ + lane];
    float pf2 = xb[2 * TAPS_ + lane];
    float pf3 = xb[3 * TAPS_ + lane];
    float pf0 = xb[4 * TAPS_ + lane];
    lds_fence();   // d_lds/lam2/xbuf[0] visible (single wave)

#define ROUND(T, XC, PFV)                                                      \
    {                                                                          \
        /* stage x_{T+1}; reload PFV with x_{T+5} (used 4 rounds later) */     \
        xbuf[(XC) ^ 1][lane] = PFV;                                            \
        {                                                                      \
            const int tn = ((T) + 5 < STEPS_) ? ((T) + 5) : (STEPS_ - 1);      \
            PFV = xb[(size_t)tn * TAPS_ + lane];                               \
        }                                                                      \
        /* row dots over x_T (broadcast b128 reads of xbuf) */                 \
        f2 xr[32];                                                             \
        f2 qa0 = pk2(0.f), qa1 = pk2(0.f), ta0 = pk2(0.f), ta1 = pk2(0.f);     \
        {                                                                      \
            const float4* xv4 = (const float4*)xbuf[(XC)];                     \
            _Pragma("unroll")                                                  \
            for (int j4 = 0; j4 < 16; ++j4) {                                  \
                const float4 v = xv4[j4];                                      \
                f2 e0; e0.x = v.x; e0.y = v.y;                                 \
                f2 e1; e1.x = v.z; e1.y = v.w;                                 \
                xr[2*j4]   = e0;                                               \
                xr[2*j4+1] = e1;                                               \
                qa0 = __builtin_elementwise_fma(Q[2*j4],    e0, qa0);          \
                qa1 = __builtin_elementwise_fma(Q[2*j4+1],  e1, qa1);          \
                ta0 = __builtin_elementwise_fma(QT[2*j4],   e0, ta0);          \
                ta1 = __builtin_elementwise_fma(QT[2*j4+1], e1, ta1);          \
            }                                                                  \
        }                                                                      \
        const float qxr = (qa0.x + qa0.y) + (qa1.x + qa1.y);                   \
        const float xqr = (ta0.x + ta0.y) + (ta1.x + ta1.y);                   \
        qxbuf[lane] = qxr;                                                     \
        xqbuf[lane] = xqr;                                                     \
        lds_fence();                                                           \
        /* den = x.Qx and y = w.x — all-lane redundant, bit-uniform */         \
        f2 qxv[32];                                                            \
        f2 da0 = pk2(0.f), da1 = pk2(0.f), ya0 = pk2(0.f), ya1 = pk2(0.f);     \
        {                                                                      \
            const float4* qv4 = (const float4*)qxbuf;                          \
            _Pragma("unroll")                                                  \
            for (int j4 = 0; j4 < 16; ++j4) {                                  \
                const float4 v = qv4[j4];                                      \
                f2 e0; e0.x = v.x; e0.y = v.y;                                 \
                f2 e1; e1.x = v.z; e1.y = v.w;                                 \
                qxv[2*j4]   = e0;                                              \
                qxv[2*j4+1] = e1;                                              \
                da0 = __builtin_elementwise_fma(xr[2*j4],   e0, da0);          \
                da1 = __builtin_elementwise_fma(xr[2*j4+1], e1, da1);          \
                ya0 = __builtin_elementwise_fma(w[2*j4],   xr[2*j4],   ya0);   \
                ya1 = __builtin_elementwise_fma(w[2*j4+1], xr[2*j4+1], ya1);   \
            }                                                                  \
        }                                                                      \
        const float pd  = (da0.x + da0.y) + (da1.x + da1.y);                   \
        const float y_h = (ya0.x + ya0.y) + (ya1.x + ya1.y);                   \
        const float2 l  = lam2[(T)];                                           \
        const float dt  = d_lds[(T)];                                          \
        const float den = fmaf(sig, pd, l.x);                                  \
        const float s   = sig * rcp_nr(den);                                   \
        const float err = dt - y_h;                                            \
        const float tr  = s * qxr;        /* own-row g-scale */                \
        sig *= l.y;                                                            \
        if (lane == 0) y_out[(size_t)b * N_ + (T)] = y_h;                      \
        const f2 s_v  = pk2(s);                                                \
        const f2 ntr  = pk2(-tr);                                              \
        const f2 nxqo = pk2(-xqr);                                             \
        const f2 errv = pk2(err);                                              \
        {                                                                      \
            const float4* qv4 = (const float4*)xqbuf;                          \
            _Pragma("unroll")                                                  \
            for (int j4 = 0; j4 < 16; ++j4) {                                  \
                const float4 v = qv4[j4];                                      \
                f2 a0; a0.x = v.x; a0.y = v.y;                                 \
                f2 a1; a1.x = v.z; a1.y = v.w;                                 \
                const f2 t0 = s_v * qxv[2*j4];     /* t_c = s*Qx[c] */         \
                const f2 t1 = s_v * qxv[2*j4+1];                               \
                w[2*j4]    = __builtin_elementwise_fma(t0, errv, w[2*j4]);     \
                w[2*j4+1]  = __builtin_elementwise_fma(t1, errv, w[2*j4+1]);   \
                Q[2*j4]    = __builtin_elementwise_fma(ntr, a0, Q[2*j4]);      \
                Q[2*j4+1]  = __builtin_elementwise_fma(ntr, a1, Q[2*j4+1]);    \
                QT[2*j4]   = __builtin_elementwise_fma(t0, nxqo, QT[2*j4]);    \
                QT[2*j4+1] = __builtin_elementwise_fma(t1, nxqo, QT[2*j4+1]);  \
            }                                                                  \
        }                                                                      \
        w_r = fmaf(tr, err, w_r);                                              \
    }

    for (int t = 0; t < STEPS_; t += 4) {
        ROUND(t + 0, 0, pf1)
        ROUND(t + 1, 1, pf2)
        ROUND(t + 2, 0, pf3)
        ROUND(t + 3, 1, pf0)
    }
#undef ROUND

    // final weights: coalesced, one element per lane
    w_out[(size_t)b * TAPS_ + lane] = w_r;
}

extern "C" void kernel_launch(void* const* d_in, const int* in_sizes, int n_in,
                              void* d_out, int out_size, void* d_ws, size_t ws_size,
                              hipStream_t stream) {
    const float* x_seq   = (const float*)d_in[0];
    const float* d_seq   = (const float*)d_in[1];
    const float* lambdas = (const float*)d_in[2];

    float* y_out = (float*)d_out;                      // B*N floats
    float* w_out = (float*)d_out + (size_t)B_ * N_;    // B*TAPS floats

    rls_kernel<<<B_, 64, 0, stream>>>(x_seq, d_seq, lambdas, y_out, w_out);
}

// Round 15
// 1134.122 us; speedup vs baseline: 2.3094x; 2.3094x over previous
//
#include <hip/hip_runtime.h>

// DeepRLSNet: batched RLS. B=64, N=T=2000, TAPS=64.
// Per step:
//   lam = clip(lambdas[t], 1e-4, 0.9999)
//   Px = P@x ; den = lam + x.Px ; g = Px/den ; y = w.x
//   w += g*(d-y) ; P = (P - outer(g, x@P))/lam   (honest x@P — R2 post-mortem)
//
// R15 = R14 rank-4 Gram/Schur cascade with the prefetch clobber FIXED.
// R14 bug: round4(t, X, XP) prefetched rows t+4..t+7's replacement into XP
// while XP still held the rows round t+4 needed -> x/d desync (absmax 9.48).
// Fix: prefetch AFTER the Gram loop (last consumer of x), into the SAME
// buffer x consumed this round, rows t+8..t+11 (next used at round t+8 —
// a full round of latency cover; loads ride across the lgkm-only barrier).
//
// Structure (4 steps per barrier round):
//   pre-barrier: Qx_i, xQ_i, w.x_i for i=0..3 (12 dots) -> LDS (8 vectors)
//   post-barrier: Gram G_ij = x_i.Qx_j (16 dots)
//   scalar cascade (Schur): G_ij -= s_k G_ik G_kj for i,j>k
//   vector cascade: QX_j -= (s_k G[k][j]) QX_k ; XQ_j -= (s_k G[j][k]) XQ_k
//   wy_j += es_k G[j][k] ; then one fused rank-4 update of Q, QT, w.
// Bitwise QT==Q^T invariant (load-bearing per R10/R11 bisect) preserved:
// own-row cascaded scalars bitwise == broadcast cascaded vectors.
// sigma-space: P = sig*Q, sig *= 1/lam per step (lam table precomputed).
// 64 blocks x 256 threads; thread t=r*4+q owns 16-wide quarter-rows.

#define B_ 64
#define N_ 2000
#define TAPS_ 64
#define STEPS_ 2000
#define VST_ 72   // padded LDS vector stride; write banks r+8q -> 2-way max

typedef float f2 __attribute__((ext_vector_type(2)));

__device__ __forceinline__ f2 pk2(float v) { f2 r; r.x = v; r.y = v; return r; }

__device__ __forceinline__ void lds_barrier() {
    // LDS-only fence + barrier: global (vmcnt) prefetch stays in flight.
    asm volatile("s_waitcnt lgkmcnt(0)\n\ts_barrier" ::: "memory");
}

__device__ __forceinline__ float clipl(float v) {
    return fminf(fmaxf(v, 1e-4f), 0.9999f);
}

// sum over the 4 q-lanes of a quad via DPP quad_perm (VALU-latency class).
__device__ __forceinline__ float quad_reduce(float v) {
    int t1 = __builtin_amdgcn_update_dpp(__float_as_int(v), __float_as_int(v),
                                         0xB1, 0xF, 0xF, false);   // xor 1
    v += __int_as_float(t1);
    int t2 = __builtin_amdgcn_update_dpp(__float_as_int(v), __float_as_int(v),
                                         0x4E, 0xF, 0xF, false);   // xor 2
    v += __int_as_float(t2);
    return v;   // bitwise-identical in all 4 lanes of the quad
}

// 1/v via v_rcp_f32 + one Newton step (~0.5 ulp).
__device__ __forceinline__ float rcp_nr(float v) {
    float r = __builtin_amdgcn_rcpf(v);
    float e = fmaf(-v, r, 1.0f);
    return fmaf(r, e, r);
}

__global__ __launch_bounds__(256, 1) void rls_kernel(
    const float* __restrict__ x_seq,   // [B, N, TAPS]
    const float* __restrict__ d_seq,   // [B, N]
    const float* __restrict__ lambdas, // [T]
    float* __restrict__ y_out,         // [B, N]
    float* __restrict__ w_out)         // [B, TAPS]
{
    const int b   = blockIdx.x;
    const int tid = threadIdx.x;
    const int r   = tid >> 2;    // row 0..63
    const int q   = tid & 3;     // quarter 0..3
    const int qb  = q << 4;

    // [parity][vec][VST_], vec: 2i=Qx_i, 2i+1=xQ_i
    __shared__ __align__(16) float  bufs[2][8][VST_];
    __shared__ __align__(16) float  d_lds[STEPS_];
    __shared__ __align__(16) float2 lam2[STEPS_];   // {clip(lam), rcp_nr(clip(lam))}

    const float* xb = x_seq + (size_t)b * N_ * TAPS_;
    const float* db = d_seq + (size_t)b * N_;

    for (int idx = tid; idx < STEPS_; idx += 256) {
        d_lds[idx] = db[idx];
        const float lc = clipl(lambdas[idx]);
        lam2[idx] = make_float2(lc, rcp_nr(lc));
    }

    f2 Q[8], QT[8], w[8];
    #pragma unroll
    for (int j = 0; j < 8; ++j) {
        Q[j].x = (qb + 2*j     == r) ? 1.0f : 0.0f;
        Q[j].y = (qb + 2*j + 1 == r) ? 1.0f : 0.0f;
        QT[j] = Q[j];
        w[j]  = pk2(0.0f);
    }
    float sig = 1.0f;   // P = sig * Q

    auto unpack4 = [](f2* dst, float4 v) {
        dst[0].x = v.x; dst[0].y = v.y; dst[1].x = v.z; dst[1].y = v.w;
    };

    // x quarters: X = rows 0-3, XP = rows 4-7
    f2 X[4][8], XP[4][8];
    #pragma unroll
    for (int i = 0; i < 4; ++i) {
        const float4* v0 = (const float4*)(xb + (size_t)i * TAPS_ + qb);
        const float4* v1 = (const float4*)(xb + (size_t)(i + 4) * TAPS_ + qb);
        #pragma unroll
        for (int j4 = 0; j4 < 4; ++j4) {
            unpack4(&X[i][2*j4],  v0[j4]);
            unpack4(&XP[i][2*j4], v1[j4]);
        }
    }
    const float* xpp = xb + 8 * TAPS_ + qb;   // prefetch ptr: row t+8

    lds_barrier();   // d_lds / lam2 visible

    // one round = steps t..t+3 consuming x; prefetches rows t+8..t+11 into
    // the SAME buffer x after its last read (Gram loop).
    auto round4 = [&](int t, f2 (&x)[4][8], int par, bool pf) {
        // ---- pre-barrier: 12 quarter-dots ----
        f2 aqx[4], axq[4], awy[4];
        #pragma unroll
        for (int i = 0; i < 4; ++i) { aqx[i]=pk2(0.f); axq[i]=pk2(0.f); awy[i]=pk2(0.f); }
        #pragma unroll
        for (int j = 0; j < 8; ++j) {
            #pragma unroll
            for (int i = 0; i < 4; ++i) {
                aqx[i] = __builtin_elementwise_fma(Q[j],  x[i][j], aqx[i]);
                axq[i] = __builtin_elementwise_fma(QT[j], x[i][j], axq[i]);
                awy[i] = __builtin_elementwise_fma(w[j],  x[i][j], awy[i]);
            }
        }
        float qxr[4], xqr[4], wy[4];
        #pragma unroll
        for (int i = 0; i < 4; ++i) {
            qxr[i] = quad_reduce(aqx[i].x + aqx[i].y);
            xqr[i] = quad_reduce(axq[i].x + axq[i].y);
            wy[i]  = quad_reduce(awy[i].x + awy[i].y);
        }
        // lane q writes vectors q and q+4 (values replicated in quad)
        {
            const float s0v = (q & 2) ? ((q & 1) ? xqr[1] : qxr[1])
                                      : ((q & 1) ? xqr[0] : qxr[0]);
            const float s1v = (q & 2) ? ((q & 1) ? xqr[3] : qxr[3])
                                      : ((q & 1) ? xqr[2] : qxr[2]);
            bufs[par][q][r]     = s0v;
            bufs[par][q + 4][r] = s1v;
        }
        lds_barrier();

        // ---- read back quarters of Qx_i, xQ_i ----
        f2 QX[4][8], XQ[4][8];
        #pragma unroll
        for (int i = 0; i < 4; ++i) {
            const float4* p0 = (const float4*)(&bufs[par][2*i][qb]);
            const float4* p1 = (const float4*)(&bufs[par][2*i + 1][qb]);
            #pragma unroll
            for (int j4 = 0; j4 < 4; ++j4) {
                unpack4(&QX[i][2*j4], p0[j4]);
                unpack4(&XQ[i][2*j4], p1[j4]);
            }
        }

        // ---- Gram: G[i][j] = x_i . Qx_j (uniform across all lanes) ----
        f2 ag[4][4];
        #pragma unroll
        for (int i = 0; i < 4; ++i)
            #pragma unroll
            for (int j = 0; j < 4; ++j) ag[i][j] = pk2(0.f);
        #pragma unroll
        for (int j = 0; j < 8; ++j) {
            #pragma unroll
            for (int i = 0; i < 4; ++i)
                #pragma unroll
                for (int jj = 0; jj < 4; ++jj)
                    ag[i][jj] = __builtin_elementwise_fma(x[i][j], QX[jj][j], ag[i][jj]);
        }
        float G[4][4];
        #pragma unroll
        for (int i = 0; i < 4; ++i)
            #pragma unroll
            for (int j = 0; j < 4; ++j)
                G[i][j] = quad_reduce(ag[i][j].x + ag[i][j].y);

        // ---- prefetch rows t+8..t+11 into x (x is dead from here on) ----
        if (pf) {
            #pragma unroll
            for (int i = 0; i < 4; ++i) {
                const float4* v0 = (const float4*)(xpp + (size_t)i * TAPS_);
                #pragma unroll
                for (int j4 = 0; j4 < 4; ++j4) unpack4(&x[i][2*j4], v0[j4]);
            }
            xpp += 4 * TAPS_;
        }

        // ---- scalar + vector cascade (all values lane-uniform / row-exact) ----
        const float4 dd = *(const float4*)&d_lds[t];
        const float dv[4] = { dd.x, dd.y, dd.z, dd.w };
        float s[4], es[4], yv[4];
        #pragma unroll
        for (int k = 0; k < 4; ++k) {
            const float2 lk = lam2[t + k];
            const float den = fmaf(sig, G[k][k], lk.x);
            s[k] = sig * rcp_nr(den);
            yv[k] = wy[k];
            const float err = dv[k] - wy[k];
            es[k] = s[k] * err;
            sig *= lk.y;
            #pragma unroll
            for (int j = k + 1; j < 4; ++j) {
                const float fkj = s[k] * G[k][j];
                const float fjk = s[k] * G[j][k];
                wy[j] = fmaf(es[k], G[j][k], wy[j]);
                const f2 nfkj = pk2(-fkj);
                const f2 nfjk = pk2(-fjk);
                #pragma unroll
                for (int e = 0; e < 8; ++e) {
                    QX[j][e] = __builtin_elementwise_fma(nfkj, QX[k][e], QX[j][e]);
                    XQ[j][e] = __builtin_elementwise_fma(nfjk, XQ[k][e], XQ[j][e]);
                }
                qxr[j] = fmaf(-fkj, qxr[k], qxr[j]);
                xqr[j] = fmaf(-fjk, xqr[k], xqr[j]);
            }
            // Schur complement on remaining Gram entries (i,j > k)
            #pragma unroll
            for (int i = k + 1; i < 4; ++i) {
                const float fik = s[k] * G[i][k];
                #pragma unroll
                for (int j = k + 1; j < 4; ++j)
                    G[i][j] = fmaf(-fik, G[k][j], G[i][j]);
            }
        }

        if (tid == 0)
            *(float4*)(y_out + (size_t)b * N_ + t) =
                make_float4(yv[0], yv[1], yv[2], yv[3]);

        // ---- fused rank-4 updates (bitwise QT == Q^T preserved) ----
        float trs[4];
        #pragma unroll
        for (int k = 0; k < 4; ++k) trs[k] = s[k] * qxr[k];
        #pragma unroll
        for (int k = 0; k < 4; ++k) {
            const f2 esv = pk2(es[k]);
            const f2 ntr = pk2(-trs[k]);
            const f2 skv = pk2(s[k]);
            const f2 nxq = pk2(-xqr[k]);
            #pragma unroll
            for (int e = 0; e < 8; ++e) {
                w[e]  = __builtin_elementwise_fma(esv, QX[k][e], w[e]);
                Q[e]  = __builtin_elementwise_fma(ntr, XQ[k][e], Q[e]);
                const f2 tq = skv * QX[k][e];
                QT[e] = __builtin_elementwise_fma(tq, nxq, QT[e]);
            }
        }
    };

    // main: rounds 0..1988 with prefetch (last prefetch -> rows 1996-1999)
    for (int t = 0; t < STEPS_ - 8; t += 8) {
        round4(t + 0, X,  0, true);
        round4(t + 4, XP, 1, true);
    }
    // epilogue: X holds rows 1992-95 (prefetched @1984), XP rows 1996-99 (@1988)
    round4(STEPS_ - 8, X,  0, false);
    round4(STEPS_ - 4, XP, 1, false);

    // ---- final weights: row-group 0 holds a full replica across q ----
    if (r == 0) {
        float4* wo = (float4*)(w_out + (size_t)b * TAPS_ + qb);
        #pragma unroll
        for (int j4 = 0; j4 < 4; ++j4)
            wo[j4] = make_float4(w[2*j4].x, w[2*j4].y, w[2*j4+1].x, w[2*j4+1].y);
    }
}

extern "C" void kernel_launch(void* const* d_in, const int* in_sizes, int n_in,
                              void* d_out, int out_size, void* d_ws, size_t ws_size,
                              hipStream_t stream) {
    const float* x_seq   = (const float*)d_in[0];
    const float* d_seq   = (const float*)d_in[1];
    const float* lambdas = (const float*)d_in[2];

    float* y_out = (float*)d_out;                      // B*N floats
    float* w_out = (float*)d_out + (size_t)B_ * N_;    // B*TAPS floats

    rls_kernel<<<B_, 256, 0, stream>>>(x_seq, d_seq, lambdas, y_out, w_out);
}